// Round 13
// baseline (4324.283 us; speedup 1.0000x reference)
//
#include <hip/hip_runtime.h>
#include <math.h>

#ifndef M_PI
#define M_PI 3.14159265358979323846
#endif

#define NXx   360
#define NXY   (NXx*NXx)
#define NTRc  32
#define NMEASc 256
#define NSTEPSc 640
#define NBCc  15
#define PADc  73
#define NVc   214

#define BROWS 45
#define NBANDS 8
#define NBLK  (NTRc*NBANDS)     // 256 blocks == 256 CUs
#define NTHREADS 1024
#define NGrow (NXx/4)           // 90
#define GPB   (BROWS*NGrow)     // 4050
#define NEDGE (4*NGrow)         // 360 edge groups (rows 0,1,43,44)
#define LDSROWS 49
#define LDSFLOATS (2*LDSROWS*NXx)
#define NSLOT 4
#define HALO_PER (NSLOT*4*NXx)  // 4 slots x 4 rows x 360

#define C2f   1.3333334f
#define C3f  (-0.083333336f)
#define ADX2  0.11111111f
#define DT2f  0.04f
#define DTf   0.2f
#define DXf   0.6f

typedef float f32x4 __attribute__((ext_vector_type(4)));

// ---- system-coherent (sc0 sc1) transport (proven R7): coherence-point ops,
// no wbl2/inv fences needed.
__device__ __forceinline__ void store4_sys(float* p, float4 v) {
    f32x4 vv; vv.x = v.x; vv.y = v.y; vv.z = v.z; vv.w = v.w;
    asm volatile("global_store_dwordx4 %0, %1, off sc0 sc1" :: "v"(p), "v"(vv) : "memory");
}
__device__ __forceinline__ float4 load4_sys(const float* p) {
    f32x4 r;
    asm volatile("global_load_dwordx4 %0, %1, off sc0 sc1\n\ts_waitcnt vmcnt(0)"
                 : "=&v"(r) : "v"(p) : "memory");
    return make_float4(r.x, r.y, r.z, r.w);
}
__device__ __forceinline__ void storei_sys(int* p, int v) {
    asm volatile("global_store_dword %0, %1, off sc0 sc1" :: "v"(p), "v"(v) : "memory");
}
__device__ __forceinline__ int loadi_sys(const int* p) {
    int r;
    asm volatile("global_load_dword %0, %1, off sc0 sc1\n\ts_waitcnt vmcnt(0)"
                 : "=&v"(r) : "v"(p) : "memory");
    return r;
}
__device__ __forceinline__ void drain_vm() {
    asm volatile("s_waitcnt vmcnt(0)" ::: "memory");
}

__global__ void velmin_kernel(const float* __restrict__ v, float* __restrict__ velmin) {
    __shared__ float s[256];
    float m = 1.5f;
    for (int i = threadIdx.x; i < NVc*NVc; i += 256) m = fminf(m, v[i]);
    s[threadIdx.x] = m;
    __syncthreads();
    for (int o = 128; o > 0; o >>= 1) {
        if (threadIdx.x < o) s[threadIdx.x] = fminf(s[threadIdx.x], s[threadIdx.x+o]);
        __syncthreads();
    }
    if (threadIdx.x == 0) *velmin = s[0];
}

__global__ void coef_kernel(const float* __restrict__ v, const float* __restrict__ velmin_p,
                            float* __restrict__ alpha, float* __restrict__ kap) {
    int idx = blockIdx.x*256 + threadIdx.x;
    if (idx >= NXY) return;
    int i = idx / NXx, j = idx - i*NXx;
    float vc = 1.5f;
    if (i >= PADc && i < PADc+NVc && j >= PADc && j < PADc+NVc)
        vc = v[(i-PADc)*NVc + (j-PADc)];
    float v2 = vc*vc;
    float al = v2 * ADX2;
    float velmin = *velmin_p;
    const float a = (float)((NBCc-1)*0.6);
    float ks = 3.0f*velmin*9.2103405f/(2.0f*a);
    float damp = 0.0f;
    int k = -1;
    if (j >= NXx-NBCc)      k = j-(NXx-NBCc);
    else if (j < NBCc)      k = NBCc-1-j;
    else if (i >= NXx-NBCc) k = i-(NXx-NBCc);
    else if (i < NBCc)      k = NBCc-1-i;
    if (k >= 0) { float r = (float)k*DXf/a; damp = ks*r*r; }
    alpha[idx] = al;
    kap[idx]   = damp*DTf;
}

__global__ void beta_kernel(const float* __restrict__ v, const int* __restrict__ in_inds,
                            float* __restrict__ beta) {
    int tr = threadIdx.x;
    if (tr >= NTRc) return;
    int idx = in_inds[tr];
    int i = idx / NXx, j = idx - i*NXx;
    float vc = 1.5f;
    if (i >= PADc && i < PADc+NVc && j >= PADc && j < PADc+NVc)
        vc = v[(i-PADc)*NVc + (j-PADc)];
    beta[tr] = DT2f*vc*vc;
}

// R7's exact schedule (proven 2250us) + register time-carry:
// each thread's own-group C(t) and prev(t-1) values passed through its own
// registers in earlier steps (rC = po of step t-1, rP = po of step t-2),
// so the cur4[Ck] and nxt4[Ck] (Pp) LDS reads are eliminated: 9 -> 7 LDS
// ops/group. LDS writes unchanged -> all cross-thread reads unaffected.
__global__ __launch_bounds__(NTHREADS, 4) void persist_kernel(
    const float* __restrict__ alpha, const float* __restrict__ kap,
    const float* __restrict__ beta, const float* __restrict__ src,
    const int* __restrict__ meas_inds, const int* __restrict__ in_inds,
    int* flags, float* haloG, float* __restrict__ out)
{
    extern __shared__ float lds[];
    const int tid  = threadIdx.x;
    const int b    = blockIdx.x;
    const int tr   = b >> 3, band = b & 7;
    const int band0 = band*BROWS;
    const int up = (tr<<3) | ((band+7)&7);
    const int dn = (tr<<3) | ((band+1)&7);

    float* buf0 = lds;
    float* buf1 = lds + LDSROWS*NXx;

    for (int i = tid; i < LDSFLOATS; i += NTHREADS) lds[i] = 0.0f;

    const float betaV = beta[tr];
    const int sCell = in_inds[tr];
    const int sr = sCell/NXx, sc = sCell - sr*NXx;

    int c0=-1,l0=0,r0=0,q0=-1; float4 A0=make_float4(0,0,0,0), K0=A0;
    int c1=-1,l1=0,r1=0,q1=-1; float4 A1=A0, K1=A0;
    int c2=-1,l2=0,r2=0,q2=-1; float4 A2=A0, K2=A0;
    int c3=-1,l3=0,r3=0,q3=-1; float4 A3=A0, K3=A0;
    int h0 = 0;

    // register time-carry state: rC = own group's field t, rP = field t-1
    float4 rC0=make_float4(0,0,0,0), rP0=rC0, rC1=rC0, rP1=rC0;
    float4 rC2=rC0, rP2=rC0, rC3=rC0, rP3=rC0;

#define INIT_SLOT(KK, Ck,Lk,Rk,Qk,AAk,KKk) { \
    int gg = tid + KK*1024; \
    if (gg < GPB) { \
        int rloc, jg; \
        if (gg < NEDGE) { int kk = gg/NGrow; jg = gg - kk*NGrow; rloc = (kk<2)?kk:(41+kk); } \
        else { int ii = gg - NEDGE; rloc = 2 + ii/NGrow; jg = ii - (ii/NGrow)*NGrow; } \
        Ck = (rloc+2)*NGrow + jg; \
        Lk = Ck + ((jg==0)?NGrow-1:-1); \
        Rk = Ck + ((jg==NGrow-1)?-(NGrow-1):1); \
        int gr = band0 + rloc, gi = gr*NXx + jg*4; \
        AAk = *(const float4*)(alpha+gi); KKk = *(const float4*)(kap+gi); \
        Qk = (gr==sr && (sc>>2)==jg) ? (sc&3) : -1; \
    } }

    INIT_SLOT(0, c0,l0,r0,q0,A0,K0)
    INIT_SLOT(1, c1,l1,r1,q1,A1,K1)
    INIT_SLOT(2, c2,l2,r2,q2,A2,K2)
    INIT_SLOT(3, c3,l3,r3,q3,A3,K3)
#undef INIT_SLOT
    if (tid < NEDGE) {
        int kk = tid/NGrow, jg = tid - kk*NGrow;
        int rloc = (kk<2)?kk:(41+kk);
        int hrow = (rloc<2)? rloc : (rloc-41);   // 0,1,2,3
        h0 = hrow*NXx + jg*4;
    }

    bool mOwn = false; int mOff = 0;
    float* outP = out + ((size_t)tr*NSTEPSc)*NMEASc + tid;
    if (tid < NMEASc) {
        int mi = meas_inds[tid]; int row = mi/NXx, col = mi - row*NXx;
        if (row >= band0 && row < band0+BROWS) { mOwn = true; mOff = (row-band0+2)*NXx + col; }
    }

    float* myHalo = haloG + (size_t)b*HALO_PER;
    float* upHalo = haloG + (size_t)up*HALO_PER;
    float* dnHalo = haloG + (size_t)dn*HALO_PER;

    __syncthreads();

// Cv comes from RCk (register), Pp from RPk (register); 6 independent LDS
// reads remain (U1,D1,U2,D2,Lv,Rv). After compute: rP <- rC, rC <- po.
#define COMPUTE_PO(Ck,Lk,Rk,Qk,AAk,KKk,RCk,RPk) \
    float4 Lv = cur4[Lk], Rv = cur4[Rk]; \
    float4 U1 = cur4[Ck-NGrow], D1 = cur4[Ck+NGrow]; \
    float4 U2 = cur4[Ck-2*NGrow], D2 = cur4[Ck+2*NGrow]; \
    float4 po; \
    { float lap = C2f*(U1.x+D1.x+Lv.w+RCk.y) + C3f*(U2.x+D2.x+Lv.z+RCk.z); \
      float t1v = 2.0f + 2.0f*(-2.5f)*AAk.x - KKk.x; float t0v = 1.0f - KKk.x; \
      po.x = AAk.x*lap + t1v*RCk.x - t0v*RPk.x; } \
    { float lap = C2f*(U1.y+D1.y+RCk.x+RCk.z) + C3f*(U2.y+D2.y+Lv.w+RCk.w); \
      float t1v = 2.0f + 2.0f*(-2.5f)*AAk.y - KKk.y; float t0v = 1.0f - KKk.y; \
      po.y = AAk.y*lap + t1v*RCk.y - t0v*RPk.y; } \
    { float lap = C2f*(U1.z+D1.z+RCk.y+RCk.w) + C3f*(U2.z+D2.z+RCk.x+Rv.x); \
      float t1v = 2.0f + 2.0f*(-2.5f)*AAk.z - KKk.z; float t0v = 1.0f - KKk.z; \
      po.z = AAk.z*lap + t1v*RCk.z - t0v*RPk.z; } \
    { float lap = C2f*(U1.w+D1.w+RCk.z+Rv.x) + C3f*(U2.w+D2.w+RCk.y+Rv.y); \
      float t1v = 2.0f + 2.0f*(-2.5f)*AAk.w - KKk.w; float t0v = 1.0f - KKk.w; \
      po.w = AAk.w*lap + t1v*RCk.w - t0v*RPk.w; } \
    if (Qk >= 0) { float add = betaV*srcT; \
        if (Qk==0) po.x += add; else if (Qk==1) po.y += add; \
        else if (Qk==2) po.z += add; else po.w += add; } \
    nxt4[Ck] = po; \
    RPk = RCk; RCk = po;

    for (int t = 0; t < NSTEPSc; ++t) {
        const int slot = t & 1;
        const int hs   = (t+1) & 3;     // halo slot for field t+1
        float* cur = (slot == 0) ? buf0 : buf1;
        float* nxt = (slot == 0) ? buf1 : buf0;
        const float4* cur4 = (const float4*)cur;
        float4* nxt4 = (float4*)nxt;
        const float srcT = src[t];

        // ---- phase 1: edge rows (0,1,43,44); publish halo(t+1) sc0sc1 ----
        if (tid < NEDGE) {
            COMPUTE_PO(c0,l0,r0,q0,A0,K0,rC0,rP0)
            store4_sys(myHalo + hs*4*NXx + h0, po);
            drain_vm();   // halo store acked at coherence point before barrier
        }
        __syncthreads();
        if (tid == 0) storei_sys(flags + b, t + 1);

        // ---- phase 2: interior rows (2..42) — overlaps flag propagation ----
        if (tid >= NEDGE) { COMPUTE_PO(c0,l0,r0,q0,A0,K0,rC0,rP0) }
        { COMPUTE_PO(c1,l1,r1,q1,A1,K1,rC1,rP1) }
        { COMPUTE_PO(c2,l2,r2,q2,A2,K2,rC2,rP2) }
        if (c3 >= 0) { COMPUTE_PO(c3,l3,r3,q3,A3,K3,rC3,rP3) }

        // ---- phase 3: wait for neighbors' field t+1 (sc0sc1 polls) ----
        if (tid == 0) {
            int g = 0;
            while (loadi_sys(flags + up) <= t)
                { __builtin_amdgcn_s_sleep(1); if (++g > 200000) break; }
        }
        if (tid == 64) {
            int g = 0;
            while (loadi_sys(flags + dn) <= t)
                { __builtin_amdgcn_s_sleep(1); if (++g > 200000) break; }
        }
        __syncthreads();

        // ---- phase 4: pull halos of field t+1 into nxt rows {0,1,47,48} ----
        if (tid < 4*NGrow) {
            int rr = tid / NGrow, jg = tid - rr*NGrow;
            const float* sp = (rr < 2) ? (upHalo + (hs*4 + 2 + rr)*NXx + jg*4)
                                       : (dnHalo + (hs*4 + (rr-2))*NXx + jg*4);
            float4 hv = load4_sys(sp);
            int ldr = (rr < 2) ? rr : (45 + rr);    // 0,1,47,48
            *(float4*)(nxt + ldr*NXx + jg*4) = hv;
        }

        // ---- phase 5: receiver gather for step t (field t+1, from LDS) ----
        if (mOwn) outP[(size_t)t*NMEASc] = nxt[mOff];

        __syncthreads();
    }
#undef COMPUTE_PO
}

extern "C" void kernel_launch(void* const* d_in, const int* in_sizes, int n_in,
                              void* d_out, int out_size, void* d_ws, size_t ws_size,
                              hipStream_t stream) {
    const float* v = (const float*)d_in[0];
    float* out = (float*)d_out;

    // workspace layout: haloG first (16B-aligned for dwordx4)
    float* haloG  = (float*)d_ws;                       // NBLK*HALO_PER
    float* alpha  = haloG + (size_t)NBLK*HALO_PER;      // 129600
    float* kap    = alpha + NXY;                        // 129600
    float* beta   = kap + NXY;                          // 32
    float* velmin = beta + NTRc;                        // 1
    float* src_d  = velmin + 1;                         // 640
    int*   meas_d = (int*)(src_d + NSTEPSc);            // 256
    int*   in_d   = meas_d + NMEASc;                    // 32
    int*   flags  = in_d + NTRc;                        // 256

    static int   h_tab[NMEASc + NTRc];
    static float h_src[NSTEPSc];
    {
        const double step = 2.0*M_PI/256.0;
        for (int k = 0; k < NMEASc; ++k) {
            double th = (double)k * step;
            int ti0 = (int)floor(160.0*cos(th) + 179.5);
            int ti1 = (int)floor(160.0*sin(th) + 179.5);
            h_tab[k] = NXx*ti0 + ti1;
        }
        for (int r = 0; r < NTRc; ++r) h_tab[NMEASc + r] = h_tab[r*(NMEASc/NTRc)];
        for (int t = 0; t < NSTEPSc; ++t) {
            double tt = (double)t * 0.2;
            double d  = tt - 3.2;
            double e  = exp(-(d*d) / 288.0);
            double s  = sin(6.283185307179586 * tt);
            h_src[t] = (float)(e * s);
        }
    }
    (void)hipMemcpyAsync(meas_d, h_tab, sizeof(int)*(NMEASc+NTRc), hipMemcpyHostToDevice, stream);
    (void)hipMemcpyAsync(src_d, h_src, sizeof(float)*NSTEPSc, hipMemcpyHostToDevice, stream);
    // zero flags + halo slots
    (void)hipMemsetAsync(haloG, 0, sizeof(float)*(size_t)NBLK*HALO_PER, stream);
    (void)hipMemsetAsync(flags, 0, sizeof(int)*NBLK, stream);

    velmin_kernel<<<1, 256, 0, stream>>>(v, velmin);
    coef_kernel<<<(NXY+255)/256, 256, 0, stream>>>(v, velmin, alpha, kap);
    beta_kernel<<<1, 64, 0, stream>>>(v, in_d, beta);

    (void)hipFuncSetAttribute((const void*)persist_kernel,
                        hipFuncAttributeMaxDynamicSharedMemorySize, LDSFLOATS*4);

    persist_kernel<<<NBLK, NTHREADS, LDSFLOATS*4, stream>>>(
        alpha, kap, beta, src_d, meas_d, in_d, flags, haloG, out);
}

// Round 14
// 2246.294 us; speedup vs baseline: 1.9251x; 1.9251x over previous
//
#include <hip/hip_runtime.h>
#include <math.h>

#ifndef M_PI
#define M_PI 3.14159265358979323846
#endif

#define NXx   360
#define NXY   (NXx*NXx)
#define NTRc  32
#define NMEASc 256
#define NSTEPSc 640
#define NBCc  15
#define PADc  73
#define NVc   214

#define BROWS 45
#define NBANDS 8
#define NBLK  (NTRc*NBANDS)     // 256 blocks == 256 CUs
#define NTHREADS 1024
#define NGrow (NXx/4)           // 90
#define GPB   (BROWS*NGrow)     // 4050
#define NEDGE (4*NGrow)         // 360 edge groups (rows 0,1,43,44)
#define LDSROWS 49
#define LDSFLOATS (2*LDSROWS*NXx)
#define NSLOT 4
#define HALO_PER (NSLOT*4*NXx)  // 4 slots x 4 rows x 360

#define C2f   1.3333334f
#define C3f  (-0.083333336f)
#define ADX2  0.11111111f
#define DT2f  0.04f
#define DTf   0.2f
#define DXf   0.6f

// native vector type for inline-asm "v" constraints (HIP float4 is a struct)
typedef float f32x4 __attribute__((ext_vector_type(4)));

// ---- system-coherent (sc0 sc1) transport: executes at chip coherence point,
// bypasses L1/L2 on both sides -> no buffer_wbl2 / buffer_inv fences needed.
__device__ __forceinline__ void store4_sys(float* p, float4 v) {
    f32x4 vv; vv.x = v.x; vv.y = v.y; vv.z = v.z; vv.w = v.w;
    asm volatile("global_store_dwordx4 %0, %1, off sc0 sc1" :: "v"(p), "v"(vv) : "memory");
}
__device__ __forceinline__ float4 load4_sys(const float* p) {
    f32x4 r;
    asm volatile("global_load_dwordx4 %0, %1, off sc0 sc1\n\ts_waitcnt vmcnt(0)"
                 : "=&v"(r) : "v"(p) : "memory");
    return make_float4(r.x, r.y, r.z, r.w);
}
__device__ __forceinline__ void storei_sys(int* p, int v) {
    asm volatile("global_store_dword %0, %1, off sc0 sc1" :: "v"(p), "v"(v) : "memory");
}
__device__ __forceinline__ int loadi_sys(const int* p) {
    int r;
    asm volatile("global_load_dword %0, %1, off sc0 sc1\n\ts_waitcnt vmcnt(0)"
                 : "=&v"(r) : "v"(p) : "memory");
    return r;
}
__device__ __forceinline__ void drain_vm() {
    asm volatile("s_waitcnt vmcnt(0)" ::: "memory");
}

__global__ void velmin_kernel(const float* __restrict__ v, float* __restrict__ velmin) {
    __shared__ float s[256];
    float m = 1.5f;
    for (int i = threadIdx.x; i < NVc*NVc; i += 256) m = fminf(m, v[i]);
    s[threadIdx.x] = m;
    __syncthreads();
    for (int o = 128; o > 0; o >>= 1) {
        if (threadIdx.x < o) s[threadIdx.x] = fminf(s[threadIdx.x], s[threadIdx.x+o]);
        __syncthreads();
    }
    if (threadIdx.x == 0) *velmin = s[0];
}

__global__ void coef_kernel(const float* __restrict__ v, const float* __restrict__ velmin_p,
                            float* __restrict__ alpha, float* __restrict__ kap) {
    int idx = blockIdx.x*256 + threadIdx.x;
    if (idx >= NXY) return;
    int i = idx / NXx, j = idx - i*NXx;
    float vc = 1.5f;
    if (i >= PADc && i < PADc+NVc && j >= PADc && j < PADc+NVc)
        vc = v[(i-PADc)*NVc + (j-PADc)];
    float v2 = vc*vc;
    float al = v2 * ADX2;
    float velmin = *velmin_p;
    const float a = (float)((NBCc-1)*0.6);
    float ks = 3.0f*velmin*9.2103405f/(2.0f*a);
    float damp = 0.0f;
    int k = -1;
    if (j >= NXx-NBCc)      k = j-(NXx-NBCc);
    else if (j < NBCc)      k = NBCc-1-j;
    else if (i >= NXx-NBCc) k = i-(NXx-NBCc);
    else if (i < NBCc)      k = NBCc-1-i;
    if (k >= 0) { float r = (float)k*DXf/a; damp = ks*r*r; }
    alpha[idx] = al;
    kap[idx]   = damp*DTf;
}

__global__ void beta_kernel(const float* __restrict__ v, const int* __restrict__ in_inds,
                            float* __restrict__ beta) {
    int tr = threadIdx.x;
    if (tr >= NTRc) return;
    int idx = in_inds[tr];
    int i = idx / NXx, j = idx - i*NXx;
    float vc = 1.5f;
    if (i >= PADc && i < PADc+NVc && j >= PADc && j < PADc+NVc)
        vc = v[(i-PADc)*NVc + (j-PADc)];
    beta[tr] = DT2f*vc*vc;
}

// Persistent LDS-resident kernel (champion, R7 = 2250us). Fence-free
// neighbor exchange:
//  - halo/flag data moves via sc0sc1 (system-coherent) ops, no wbl2/inv.
//  - 4 halo slots (slot = field & 3): writer reuses a slot only when >= 3
//    steps past the reader's gated position (max drift 1) -> race-free.
//  - edge-first: edges -> drain -> barrier -> flag publish -> interior ->
//    poll -> barrier -> pull next halos -> gather.
// Measured (R7): LDS-pipe-bound; step time = LDS ops (6835cy) + conflicts
// (1620cy). All 6 attempted deviations (R8-R13) regressed: ILP loss,
// sync exposure, or register spill. This schedule is the verified floor.
__global__ __launch_bounds__(NTHREADS, 4) void persist_kernel(
    const float* __restrict__ alpha, const float* __restrict__ kap,
    const float* __restrict__ beta, const float* __restrict__ src,
    const int* __restrict__ meas_inds, const int* __restrict__ in_inds,
    int* flags, float* haloG, float* __restrict__ out)
{
    extern __shared__ float lds[];
    const int tid  = threadIdx.x;
    const int b    = blockIdx.x;
    const int tr   = b >> 3, band = b & 7;
    const int band0 = band*BROWS;
    const int up = (tr<<3) | ((band+7)&7);
    const int dn = (tr<<3) | ((band+1)&7);

    float* buf0 = lds;
    float* buf1 = lds + LDSROWS*NXx;

    for (int i = tid; i < LDSFLOATS; i += NTHREADS) lds[i] = 0.0f;

    const float betaV = beta[tr];
    const int sCell = in_inds[tr];
    const int sr = sCell/NXx, sc = sCell - sr*NXx;

    int c0=-1,l0=0,r0=0,q0=-1; float4 A0=make_float4(0,0,0,0), K0=A0;
    int c1=-1,l1=0,r1=0,q1=-1; float4 A1=A0, K1=A0;
    int c2=-1,l2=0,r2=0,q2=-1; float4 A2=A0, K2=A0;
    int c3=-1,l3=0,r3=0,q3=-1; float4 A3=A0, K3=A0;
    int h0 = 0;

#define INIT_SLOT(KK, Ck,Lk,Rk,Qk,AAk,KKk) { \
    int gg = tid + KK*1024; \
    if (gg < GPB) { \
        int rloc, jg; \
        if (gg < NEDGE) { int kk = gg/NGrow; jg = gg - kk*NGrow; rloc = (kk<2)?kk:(41+kk); } \
        else { int ii = gg - NEDGE; rloc = 2 + ii/NGrow; jg = ii - (ii/NGrow)*NGrow; } \
        Ck = (rloc+2)*NGrow + jg; \
        Lk = Ck + ((jg==0)?NGrow-1:-1); \
        Rk = Ck + ((jg==NGrow-1)?-(NGrow-1):1); \
        int gr = band0 + rloc, gi = gr*NXx + jg*4; \
        AAk = *(const float4*)(alpha+gi); KKk = *(const float4*)(kap+gi); \
        Qk = (gr==sr && (sc>>2)==jg) ? (sc&3) : -1; \
    } }

    INIT_SLOT(0, c0,l0,r0,q0,A0,K0)
    INIT_SLOT(1, c1,l1,r1,q1,A1,K1)
    INIT_SLOT(2, c2,l2,r2,q2,A2,K2)
    INIT_SLOT(3, c3,l3,r3,q3,A3,K3)
#undef INIT_SLOT
    if (tid < NEDGE) {
        int kk = tid/NGrow, jg = tid - kk*NGrow;
        int rloc = (kk<2)?kk:(41+kk);
        int hrow = (rloc<2)? rloc : (rloc-41);   // 0,1,2,3
        h0 = hrow*NXx + jg*4;
    }

    bool mOwn = false; int mOff = 0;
    float* outP = out + ((size_t)tr*NSTEPSc)*NMEASc + tid;
    if (tid < NMEASc) {
        int mi = meas_inds[tid]; int row = mi/NXx, col = mi - row*NXx;
        if (row >= band0 && row < band0+BROWS) { mOwn = true; mOff = (row-band0+2)*NXx + col; }
    }

    float* myHalo = haloG + (size_t)b*HALO_PER;
    float* upHalo = haloG + (size_t)up*HALO_PER;
    float* dnHalo = haloG + (size_t)dn*HALO_PER;

    __syncthreads();

#define COMPUTE_PO(Ck,Lk,Rk,Qk,AAk,KKk) \
    float4 Cv = cur4[Ck], Lv = cur4[Lk], Rv = cur4[Rk]; \
    float4 U1 = cur4[Ck-NGrow], D1 = cur4[Ck+NGrow]; \
    float4 U2 = cur4[Ck-2*NGrow], D2 = cur4[Ck+2*NGrow]; \
    float4 Pp = nxt4[Ck]; float4 po; \
    { float lap = C2f*(U1.x+D1.x+Lv.w+Cv.y) + C3f*(U2.x+D2.x+Lv.z+Cv.z); \
      float t1v = 2.0f + 2.0f*(-2.5f)*AAk.x - KKk.x; float t0v = 1.0f - KKk.x; \
      po.x = AAk.x*lap + t1v*Cv.x - t0v*Pp.x; } \
    { float lap = C2f*(U1.y+D1.y+Cv.x+Cv.z) + C3f*(U2.y+D2.y+Lv.w+Cv.w); \
      float t1v = 2.0f + 2.0f*(-2.5f)*AAk.y - KKk.y; float t0v = 1.0f - KKk.y; \
      po.y = AAk.y*lap + t1v*Cv.y - t0v*Pp.y; } \
    { float lap = C2f*(U1.z+D1.z+Cv.y+Cv.w) + C3f*(U2.z+D2.z+Cv.x+Rv.x); \
      float t1v = 2.0f + 2.0f*(-2.5f)*AAk.z - KKk.z; float t0v = 1.0f - KKk.z; \
      po.z = AAk.z*lap + t1v*Cv.z - t0v*Pp.z; } \
    { float lap = C2f*(U1.w+D1.w+Cv.z+Rv.x) + C3f*(U2.w+D2.w+Cv.y+Rv.y); \
      float t1v = 2.0f + 2.0f*(-2.5f)*AAk.w - KKk.w; float t0v = 1.0f - KKk.w; \
      po.w = AAk.w*lap + t1v*Cv.w - t0v*Pp.w; } \
    if (Qk >= 0) { float add = betaV*srcT; \
        if (Qk==0) po.x += add; else if (Qk==1) po.y += add; \
        else if (Qk==2) po.z += add; else po.w += add; } \
    nxt4[Ck] = po;

    for (int t = 0; t < NSTEPSc; ++t) {
        const int slot = t & 1;
        const int hs   = (t+1) & 3;     // halo slot for field t+1
        float* cur = (slot == 0) ? buf0 : buf1;
        float* nxt = (slot == 0) ? buf1 : buf0;
        const float4* cur4 = (const float4*)cur;
        float4* nxt4 = (float4*)nxt;
        const float srcT = src[t];

        // ---- phase 1: edge rows (0,1,43,44); publish halo(t+1) sc0sc1 ----
        if (tid < NEDGE) {
            COMPUTE_PO(c0,l0,r0,q0,A0,K0)
            store4_sys(myHalo + hs*4*NXx + h0, po);
            drain_vm();   // halo store acked at coherence point before barrier
        }
        __syncthreads();
        if (tid == 0) storei_sys(flags + b, t + 1);

        // ---- phase 2: interior rows (2..42) — overlaps flag propagation ----
        if (tid >= NEDGE) { COMPUTE_PO(c0,l0,r0,q0,A0,K0) }
        { COMPUTE_PO(c1,l1,r1,q1,A1,K1) }
        { COMPUTE_PO(c2,l2,r2,q2,A2,K2) }
        if (c3 >= 0) { COMPUTE_PO(c3,l3,r3,q3,A3,K3) }

        // ---- phase 3: wait for neighbors' field t+1 (sc0sc1 polls, no inv) ----
        if (tid == 0) {
            int g = 0;
            while (loadi_sys(flags + up) <= t)
                { __builtin_amdgcn_s_sleep(1); if (++g > 200000) break; }
        }
        if (tid == 64) {
            int g = 0;
            while (loadi_sys(flags + dn) <= t)
                { __builtin_amdgcn_s_sleep(1); if (++g > 200000) break; }
        }
        __syncthreads();

        // ---- phase 4: pull halos of field t+1 into nxt rows {0,1,47,48} ----
        if (tid < 4*NGrow) {
            int rr = tid / NGrow, jg = tid - rr*NGrow;
            const float* sp = (rr < 2) ? (upHalo + (hs*4 + 2 + rr)*NXx + jg*4)
                                       : (dnHalo + (hs*4 + (rr-2))*NXx + jg*4);
            float4 hv = load4_sys(sp);
            int ldr = (rr < 2) ? rr : (45 + rr);    // 0,1,47,48
            *(float4*)(nxt + ldr*NXx + jg*4) = hv;
        }

        // ---- phase 5: receiver gather for step t (field t+1, from LDS) ----
        if (mOwn) outP[(size_t)t*NMEASc] = nxt[mOff];

        __syncthreads();
    }
#undef COMPUTE_PO
}

extern "C" void kernel_launch(void* const* d_in, const int* in_sizes, int n_in,
                              void* d_out, int out_size, void* d_ws, size_t ws_size,
                              hipStream_t stream) {
    const float* v = (const float*)d_in[0];
    float* out = (float*)d_out;

    // workspace layout: haloG first (16B-aligned for dwordx4)
    float* haloG  = (float*)d_ws;                       // NBLK*HALO_PER
    float* alpha  = haloG + (size_t)NBLK*HALO_PER;      // 129600
    float* kap    = alpha + NXY;                        // 129600
    float* beta   = kap + NXY;                          // 32
    float* velmin = beta + NTRc;                        // 1
    float* src_d  = velmin + 1;                         // 640
    int*   meas_d = (int*)(src_d + NSTEPSc);            // 256
    int*   in_d   = meas_d + NMEASc;                    // 32
    int*   flags  = in_d + NTRc;                        // 256

    static int   h_tab[NMEASc + NTRc];
    static float h_src[NSTEPSc];
    {
        const double step = 2.0*M_PI/256.0;
        for (int k = 0; k < NMEASc; ++k) {
            double th = (double)k * step;
            int ti0 = (int)floor(160.0*cos(th) + 179.5);
            int ti1 = (int)floor(160.0*sin(th) + 179.5);
            h_tab[k] = NXx*ti0 + ti1;
        }
        for (int r = 0; r < NTRc; ++r) h_tab[NMEASc + r] = h_tab[r*(NMEASc/NTRc)];
        for (int t = 0; t < NSTEPSc; ++t) {
            double tt = (double)t * 0.2;
            double d  = tt - 3.2;
            double e  = exp(-(d*d) / 288.0);
            double s  = sin(6.283185307179586 * tt);
            h_src[t] = (float)(e * s);
        }
    }
    (void)hipMemcpyAsync(meas_d, h_tab, sizeof(int)*(NMEASc+NTRc), hipMemcpyHostToDevice, stream);
    (void)hipMemcpyAsync(src_d, h_src, sizeof(float)*NSTEPSc, hipMemcpyHostToDevice, stream);
    // zero flags + halo slots
    (void)hipMemsetAsync(haloG, 0, sizeof(float)*(size_t)NBLK*HALO_PER, stream);
    (void)hipMemsetAsync(flags, 0, sizeof(int)*NBLK, stream);

    velmin_kernel<<<1, 256, 0, stream>>>(v, velmin);
    coef_kernel<<<(NXY+255)/256, 256, 0, stream>>>(v, velmin, alpha, kap);
    beta_kernel<<<1, 64, 0, stream>>>(v, in_d, beta);

    (void)hipFuncSetAttribute((const void*)persist_kernel,
                        hipFuncAttributeMaxDynamicSharedMemorySize, LDSFLOATS*4);

    persist_kernel<<<NBLK, NTHREADS, LDSFLOATS*4, stream>>>(
        alpha, kap, beta, src_d, meas_d, in_d, flags, haloG, out);
}